// Round 17
// baseline (272.197 us; speedup 1.0000x reference)
//
#include <hip/hip_runtime.h>
#include <math.h>

typedef float    f32x4 __attribute__((ext_vector_type(4)));
typedef unsigned u32x4 __attribute__((ext_vector_type(4)));

// ws layout (uint32 words):
//   [0     .. 16384)  histC  (exact low-bits hist over selected 2^14 window)
//   [16384 .. 20480)  hist12 (top-12-bit histogram)
//   [20480 .. 20544)  hist64 (64 sub-bins of width 2^14 within selected b12)
//   [20544 .. 20560)  ctrl: [3]=cand_count  (all other selection state is
//                            recomputed per-block from finalized histograms)
//   [20560 .. +CAP)   candidate INDICES (element idx) of selected b12
#define HC_OFF     0u
#define H12_OFF    16384u
#define H64_OFF    20480u
#define CTRL_OFF   20544u
#define ZERO_WORDS 20560u
#define CAND_OFF   20560u
#define CAND_CAP   900000u
#define LBUF       2048u

#define FLOOR_BITS 0x36000000u // bits(2^-19): below this, cheap unreliable

// TAGGING (r9/r14/r15/r16-proven): known -> loss_bits & ~1 (even, FINAL);
// unknown -> refined_bits | 1 (odd). <=1-ulp perturbation absorbed by
// margins (+2); 2^20/2^14 bin membership tag-invariant; exact threshold
// bits stay untagged.

// --- exact softplus (UNCHANGED from passing rounds 1-16) -----------------
__device__ __forceinline__ float softplus_exact(float x) {
    float ax = fabsf(x);
    float e = (float)exp(-(double)ax);
    float l = (float)log1p((double)e);
    return fmaxf(x, 0.0f) + l;
}
__device__ __forceinline__ unsigned exact_bits(float x) {
    return __float_as_uint(softplus_exact(x));
}

// --- refinement: cheap + margin-gated exact; DETERMINISTIC fn of x -------
__device__ __forceinline__ unsigned refine_core(float x, float ax, float e,
                                                float sp) {
    unsigned cb = __float_as_uint(sp);
    float mf = 64.0f + 8.0f * ax;
    if (x < 0.0f) mf += __builtin_amdgcn_rcpf(e);
    bool need = (cb < FLOOR_BITS) || (mf >= 524288.0f);
    if (!need) {
        unsigned m = (unsigned)mf;
        unsigned low = cb & 0xFFFFFu;
        need = (low < m) || (low >= 0x100000u - m);
    }
    if (need) cb = exact_bits(x);
    return cb;
}
__device__ __forceinline__ unsigned refine_A(float x) {
    float ax = fabsf(x);
    float e = __expf(-ax);
    float sp = fmaxf(x, 0.0f) + __logf(1.0f + e);
    return refine_core(x, ax, e, sp);
}

// === per-block recomputation of selection state (pure fns of finalized ws)
// k2 logic: 12-bit bin, kprime, bin margin.  blockDim.x must be 256.
__device__ void sel12_block(const unsigned* __restrict__ hist12, int epoch,
                            int* o_b12, unsigned* o_kprime, unsigned* o_mb) {
    __shared__ unsigned long long s12_chunk[256];
    __shared__ int s12_b;
    __shared__ unsigned s12_kp, s12_mb;
    int t = threadIdx.x;
    unsigned long long s = 0;
    for (int j = 0; j < 16; ++j) s += hist12[t * 16 + j];
    s12_chunk[t] = s;
    __syncthreads();
    if (t == 0) {
        unsigned long long tot = 0;
        for (int c = 0; c < 256; ++c) tot += s12_chunk[c];
        float percent = fminf((float)epoch * 0.1f, 1.0f);
        float nf = (float)tot;              // astype(float32)
        float kr = rintf(nf * percent);     // jnp.round half-to-even
        long long k = (long long)kr;        // astype(int32)
        if (k < 1) k = 1;
        long long cum = 0;
        int b = -1;
        long long kprime = 0;
        for (int c = 255; c >= 0; --c) {
            if (cum + (long long)s12_chunk[c] >= k) {
                long long cc = cum;
                for (int j = 15; j >= 0; --j) {
                    unsigned v = hist12[c * 16 + j];
                    if (cc + (long long)v >= k) {
                        b = c * 16 + j;
                        kprime = k - cc;
                        break;
                    }
                    cc += v;
                }
                break;
            }
            cum += s12_chunk[c];
        }
        unsigned mb_out = 0u;
        if (b >= 0) {
            unsigned lo12 = (unsigned)b << 20;
            double vlo = (double)__uint_as_float(lo12);
            double vhi = (double)__uint_as_float(lo12 + 0xFFFFFu);
            double mb = 1e9;
            if (vlo > 1e-30) {
                double xlo = vlo + log1p(-exp(-vlo)) - 0.001;  // inv_softplus
                double xhi = vhi + log1p(-exp(-vhi)) + 0.001;
                double axmax = fmax(fabs(xlo), fabs(xhi));
                mb = 64.0 + 8.0 * ceil(axmax);
                if (xlo < 0.0) mb += exp(fmin(-xlo, 30.0));
                mb *= 2.0;                  // safety factor
            }
            mb_out = (mb >= 8192.0) ? 8192u : (unsigned)mb;
        }
        s12_b = b;
        s12_kp = (unsigned)kprime;
        s12_mb = mb_out;
    }
    __syncthreads();
    *o_b12 = s12_b;
    *o_kprime = s12_kp;
    *o_mb = s12_mb;
}

// k4 logic: 2^14-wide window within b12.
__device__ void sel64_block(const unsigned* __restrict__ h64, unsigned b12u,
                            long long kprime, unsigned* o_wlo,
                            unsigned* o_kpp) {
    __shared__ unsigned s64_wlo, s64_kpp;
    if (threadIdx.x == 0) {
        long long cum = 0;
        int sbin = 0;
        long long kpp = 1;
        for (int j = 63; j >= 0; --j) {
            unsigned v = h64[j];
            if (cum + (long long)v >= kprime) {
                sbin = j;
                kpp = kprime - cum;
                break;
            }
            cum += v;
        }
        s64_wlo = (b12u << 20) + ((unsigned)sbin << 14);
        s64_kpp = (unsigned)kpp;
    }
    __syncthreads();
    *o_wlo = s64_wlo;
    *o_kpp = s64_kpp;
}

// k6 logic: exact threshold bits from histC.
__device__ void selwin_block(const unsigned* __restrict__ histC, unsigned wlo,
                             long long kpp, unsigned* o_thr) {
    __shared__ unsigned long long sw_csum[256];
    __shared__ unsigned sw_thr;
    int t = threadIdx.x;
    unsigned long long s = 0;
    for (int j = 0; j < 64; ++j) s += histC[t * 64 + j];
    sw_csum[t] = s;
    __syncthreads();
    if (t == 0) {
        long long cum = 0;
        int sel = 0;
        long long rem = kpp;
        for (int c = 255; c >= 0; --c) {
            if (cum + (long long)sw_csum[c] >= kpp) {
                sel = c;
                rem = kpp - cum;
                break;
            }
            cum += sw_csum[c];
        }
        long long cc = 0;
        int bsel = 0;
        for (int j = 63; j >= 0; --j) {
            unsigned v = histC[sel * 64 + j];
            if (cc + (long long)v >= rem) {
                bsel = j;
                break;
            }
            cc += v;
        }
        sw_thr = wlo + (unsigned)(sel * 64 + bsel);
    }
    __syncthreads();
    *o_thr = sw_thr;
}

// --- kA per-element (r14/r15/r16-proven) ----------------------------------
__device__ __forceinline__ unsigned kA_elem(float x, float t,
                                            unsigned* __restrict__ sh) {
    float ax = fabsf(x);
    float e = __expf(-ax);
    float sp = fmaxf(x, 0.0f) + __logf(1.0f + e);
    unsigned outb;
    if (isnan(t)) {
        unsigned cb = refine_core(x, ax, e, sp) | 1u;   // tag odd
        if (cb != 1u) atomicAdd(&sh[cb >> 20], 1u);     // count_nonzero
        outb = cb;
    } else {
        float loss = sp - x * t;                    // >= 0 always
        outb = __float_as_uint(loss) & ~1u;         // tag even: FINAL value
    }
    return outb;
}

// --- kA: stream logits+targets; store tagged bits to out; hist12 ---------
__global__ __launch_bounds__(256) void kA_store_hist(
    const float* __restrict__ lg, const float* __restrict__ tg,
    float* __restrict__ out, unsigned* __restrict__ ws, long long n) {
    __shared__ unsigned sh[4096];
    for (int i = threadIdx.x; i < 4096; i += 256) sh[i] = 0;
    __syncthreads();

    long long n8 = n >> 3;
    long long tid = (long long)blockIdx.x * 256 + threadIdx.x;
    long long stride = (long long)gridDim.x * 256;
    const f32x4* lg4 = (const f32x4*)lg;
    const f32x4* tg4 = (const f32x4*)tg;
    f32x4* out4 = (f32x4*)out;

    if (n8 % stride == 0) {
        long long iters = n8 / stride;
        f32x4 xa0, xb0, ta0, tb0, xa1, xb1, ta1, tb1;
        {
            long long i = tid;
            xa0 = lg4[2 * i]; xb0 = lg4[2 * i + 1];
            ta0 = __builtin_nontemporal_load(&tg4[2 * i]);
            tb0 = __builtin_nontemporal_load(&tg4[2 * i + 1]);
        }
        if (iters > 1) {
            long long i = tid + stride;
            xa1 = lg4[2 * i]; xb1 = lg4[2 * i + 1];
            ta1 = __builtin_nontemporal_load(&tg4[2 * i]);
            tb1 = __builtin_nontemporal_load(&tg4[2 * i + 1]);
        }
        for (long long it = 0; it < iters; ++it) {
            f32x4 pa, pb, pta, ptb;
            if (it + 2 < iters) {
                long long i = tid + (it + 2) * stride;
                pa = lg4[2 * i]; pb = lg4[2 * i + 1];
                pta = __builtin_nontemporal_load(&tg4[2 * i]);
                ptb = __builtin_nontemporal_load(&tg4[2 * i + 1]);
            }
            long long i = tid + it * stride;
            f32x4 oa, ob_;
            oa.x = __uint_as_float(kA_elem(xa0.x, ta0.x, sh));
            oa.y = __uint_as_float(kA_elem(xa0.y, ta0.y, sh));
            oa.z = __uint_as_float(kA_elem(xa0.z, ta0.z, sh));
            oa.w = __uint_as_float(kA_elem(xa0.w, ta0.w, sh));
            ob_.x = __uint_as_float(kA_elem(xb0.x, tb0.x, sh));
            ob_.y = __uint_as_float(kA_elem(xb0.y, tb0.y, sh));
            ob_.z = __uint_as_float(kA_elem(xb0.z, tb0.z, sh));
            ob_.w = __uint_as_float(kA_elem(xb0.w, tb0.w, sh));
            out4[2 * i] = oa;
            out4[2 * i + 1] = ob_;
            xa0 = xa1; xb0 = xb1; ta0 = ta1; tb0 = tb1;
            xa1 = pa; xb1 = pb; ta1 = pta; tb1 = ptb;
        }
    } else {
        for (long long i = tid; i < n8; i += stride) {
            f32x4 xa = lg4[2 * i], xb = lg4[2 * i + 1];
            f32x4 ta = tg4[2 * i], tb = tg4[2 * i + 1];
            f32x4 oa, ob_;
            oa.x = __uint_as_float(kA_elem(xa.x, ta.x, sh));
            oa.y = __uint_as_float(kA_elem(xa.y, ta.y, sh));
            oa.z = __uint_as_float(kA_elem(xa.z, ta.z, sh));
            oa.w = __uint_as_float(kA_elem(xa.w, ta.w, sh));
            ob_.x = __uint_as_float(kA_elem(xb.x, tb.x, sh));
            ob_.y = __uint_as_float(kA_elem(xb.y, tb.y, sh));
            ob_.z = __uint_as_float(kA_elem(xb.z, tb.z, sh));
            ob_.w = __uint_as_float(kA_elem(xb.w, tb.w, sh));
            out4[2 * i] = oa;
            out4[2 * i + 1] = ob_;
        }
    }
    if (tid == 0) {   // scalar tail
        for (long long q = (n >> 3) << 3; q < n; ++q)
            out[q] = __uint_as_float(kA_elem(lg[q], tg[q], sh));
    }
    __syncthreads();
    unsigned* hist12 = ws + H12_OFF;
    for (int q = threadIdx.x; q < 4096; q += 256)
        if (sh[q]) atomicAdd(&hist12[q], sh[q]);
}

// --- kB: (inline k2) zero definite rejects, hist64, compact candidate idx -
__device__ __forceinline__ void kB_elem(unsigned u, long long idx,
                                        unsigned lo12, unsigned hi12,
                                        unsigned medge,
                                        const float* __restrict__ lg,
                                        unsigned* __restrict__ ob,
                                        unsigned* __restrict__ sh,
                                        unsigned* __restrict__ buf,
                                        unsigned* __restrict__ lcnt) {
    if ((u & 1u) && u != 1u) {          // unknown, nonzero loss
        if (u >= hi12) {
            ob[idx] = 0u;               // definite reject: final zero
        } else if (u >= lo12) {         // candidate
            unsigned rB = u;
            unsigned d = u & 16383u;
            if (d < medge || d >= 16384u - medge)
                rB = exact_bits(lg[idx]) | 1u;   // edge: exact (tagged bin)
            atomicAdd(&sh[(rB >> 14) & 63u], 1u);
            unsigned li = atomicAdd(lcnt, 1u);
            if (li < LBUF) buf[li] = (unsigned)idx;
        }
    }
}

__global__ __launch_bounds__(256) void kB_zero(
    const float* __restrict__ lg, unsigned* __restrict__ ob,
    unsigned* __restrict__ ws, const int* __restrict__ epoch_ptr,
    long long n) {
    int b12i;
    unsigned kprime, mb;
    sel12_block(ws + H12_OFF, epoch_ptr[0], &b12i, &kprime, &mb);
    if (b12i < 0) return;
    unsigned b12 = (unsigned)b12i;
    unsigned lo12 = b12 << 20;
    unsigned hi12 = (b12 >= 4095u) ? 0xFFFFFFFFu : (lo12 + (1u << 20));
    unsigned medge = mb + 2u;           // +2: tag absorption

    __shared__ unsigned sh[64];
    __shared__ unsigned buf[LBUF];
    __shared__ unsigned lcnt, gbase;
    if (threadIdx.x < 64) sh[threadIdx.x] = 0;
    if (threadIdx.x == 0) lcnt = 0;
    __syncthreads();

    unsigned* cand = ws + CAND_OFF;
    unsigned* cnt = ws + CTRL_OFF + 3;

    long long n8 = n >> 3;
    long long tid = (long long)blockIdx.x * 256 + threadIdx.x;
    long long stride = (long long)gridDim.x * 256;
    const u32x4* o4 = (const u32x4*)ob;

    if (n8 % stride == 0) {
        long long iters = n8 / stride;
        u32x4 ua0, ub0, ua1, ub1;
        {
            long long i = tid;
            ua0 = o4[2 * i]; ub0 = o4[2 * i + 1];
        }
        if (iters > 1) {
            long long i = tid + stride;
            ua1 = o4[2 * i]; ub1 = o4[2 * i + 1];
        }
        for (long long it = 0; it < iters; ++it) {
            u32x4 pa, pb;
            if (it + 2 < iters) {
                long long i = tid + (it + 2) * stride;
                pa = o4[2 * i]; pb = o4[2 * i + 1];
            }
            long long i = tid + it * stride;
            long long base = i * 8;
            kB_elem(ua0.x, base + 0, lo12, hi12, medge, lg, ob, sh, buf, &lcnt);
            kB_elem(ua0.y, base + 1, lo12, hi12, medge, lg, ob, sh, buf, &lcnt);
            kB_elem(ua0.z, base + 2, lo12, hi12, medge, lg, ob, sh, buf, &lcnt);
            kB_elem(ua0.w, base + 3, lo12, hi12, medge, lg, ob, sh, buf, &lcnt);
            kB_elem(ub0.x, base + 4, lo12, hi12, medge, lg, ob, sh, buf, &lcnt);
            kB_elem(ub0.y, base + 5, lo12, hi12, medge, lg, ob, sh, buf, &lcnt);
            kB_elem(ub0.z, base + 6, lo12, hi12, medge, lg, ob, sh, buf, &lcnt);
            kB_elem(ub0.w, base + 7, lo12, hi12, medge, lg, ob, sh, buf, &lcnt);
            ua0 = ua1; ub0 = ub1;
            ua1 = pa; ub1 = pb;
        }
    } else {
        for (long long i = tid; i < n8; i += stride) {
            u32x4 ua = o4[2 * i], ub = o4[2 * i + 1];
            long long base = i * 8;
            kB_elem(ua.x, base + 0, lo12, hi12, medge, lg, ob, sh, buf, &lcnt);
            kB_elem(ua.y, base + 1, lo12, hi12, medge, lg, ob, sh, buf, &lcnt);
            kB_elem(ua.z, base + 2, lo12, hi12, medge, lg, ob, sh, buf, &lcnt);
            kB_elem(ua.w, base + 3, lo12, hi12, medge, lg, ob, sh, buf, &lcnt);
            kB_elem(ub.x, base + 4, lo12, hi12, medge, lg, ob, sh, buf, &lcnt);
            kB_elem(ub.y, base + 5, lo12, hi12, medge, lg, ob, sh, buf, &lcnt);
            kB_elem(ub.z, base + 6, lo12, hi12, medge, lg, ob, sh, buf, &lcnt);
            kB_elem(ub.w, base + 7, lo12, hi12, medge, lg, ob, sh, buf, &lcnt);
        }
    }
    if (tid == 0) {   // scalar tail
        for (long long q = (n >> 3) << 3; q < n; ++q)
            kB_elem(ob[q], q, lo12, hi12, medge, lg, ob, sh, buf, &lcnt);
    }
    __syncthreads();
    if (threadIdx.x < 64 && sh[threadIdx.x])
        atomicAdd(&ws[H64_OFF + threadIdx.x], sh[threadIdx.x]);
    if (threadIdx.x == 0) {
        // on LDS overflow, poison count -> kC/kD take full-scan fallback
        unsigned add = (lcnt > LBUF) ? (CAND_CAP + 1u) : lcnt;
        gbase = atomicAdd(cnt, add);
    }
    __syncthreads();
    unsigned c2 = lcnt < LBUF ? lcnt : LBUF;
    for (unsigned q = threadIdx.x; q < c2; q += 256) {
        unsigned gi = gbase + q;
        if (gi < CAND_CAP) cand[gi] = buf[q];
    }
}

// --- kC: (inline k2+k4) exact histogram over the selected window ----------
__global__ __launch_bounds__(256) void kC_histwin(
    const float* __restrict__ lg, const unsigned* __restrict__ ob,
    unsigned* __restrict__ ws, const int* __restrict__ epoch_ptr,
    long long n) {
    int b12i;
    unsigned kprime, mb;
    sel12_block(ws + H12_OFF, epoch_ptr[0], &b12i, &kprime, &mb);
    if (b12i < 0) return;
    unsigned b12 = (unsigned)b12i;
    unsigned wlo, kpp;
    sel64_block(ws + H64_OFF, b12, (long long)kprime, &wlo, &kpp);
    unsigned whi = wlo + 16384u;
    unsigned medge = mb + 2u;           // must match kB exactly
    unsigned lo12 = b12 << 20;
    unsigned hi12 = (b12 >= 4095u) ? 0xFFFFFFFFu : (lo12 + (1u << 20));
    unsigned glo = (wlo - lo12 > medge) ? wlo - medge : lo12;
    unsigned ghi = (hi12 - whi > medge) ? whi + medge : hi12;
    unsigned count = ws[CTRL_OFF + 3];

    long long tid = (long long)blockIdx.x * 256 + threadIdx.x;
    long long stride = (long long)gridDim.x * 256;

    if (count <= CAND_CAP) {
        const unsigned* cand = ws + CAND_OFF;
        for (long long i = tid; i < (long long)count; i += stride) {
            unsigned idx = cand[i];
            float x = lg[idx];
            unsigned u = refine_A(x) | 1u;    // bit-identical to stored bits
            if (u >= glo && u < ghi) {
                unsigned eb = exact_bits(x);  // TRUE untagged bits
                unsigned rB = u;
                unsigned d = u & 16383u;
                if (d < medge || d >= 16384u - medge) rB = eb | 1u;
                if (rB >= wlo && rB < whi) {
                    unsigned off = eb - wlo;
                    if (off < 16384u) atomicAdd(&ws[HC_OFF + off], 1u);
                }
            }
        }
    } else {
        // overflow fallback: rescan full out array (never expected)
        long long n4 = n >> 2;
        const u32x4* o4 = (const u32x4*)ob;
        for (long long i = tid; i < n4; i += stride) {
            u32x4 u4 = o4[i];
            unsigned us[4] = {u4.x, u4.y, u4.z, u4.w};
#pragma unroll
            for (int c = 0; c < 4; ++c) {
                unsigned u = us[c];
                if ((u & 1u) && u != 1u && u >= glo && u < ghi) {
                    float x = lg[i * 4 + c];
                    unsigned eb = exact_bits(x);
                    unsigned rB = u;
                    unsigned d = u & 16383u;
                    if (d < medge || d >= 16384u - medge) rB = eb | 1u;
                    if (rB >= wlo && rB < whi) {
                        unsigned off = eb - wlo;
                        if (off < 16384u) atomicAdd(&ws[HC_OFF + off], 1u);
                    }
                }
            }
        }
        if (tid == 0) {
            for (long long q = (n4 << 2); q < n; ++q) {
                unsigned u = ob[q];
                if ((u & 1u) && u != 1u && u >= glo && u < ghi) {
                    unsigned eb = exact_bits(lg[q]);
                    unsigned rB = u;
                    unsigned d = u & 16383u;
                    if (d < medge || d >= 16384u - medge) rB = eb | 1u;
                    if (rB >= wlo && rB < whi) {
                        unsigned off = eb - wlo;
                        if (off < 16384u) atomicAdd(&ws[HC_OFF + off], 1u);
                    }
                }
            }
        }
    }
}

// --- kD: (inline k2+k4+k6) apply threshold --------------------------------
__global__ __launch_bounds__(256) void kD_apply(
    const float* __restrict__ lg, unsigned* __restrict__ ob,
    unsigned* __restrict__ ws, const int* __restrict__ epoch_ptr,
    long long n) {
    int b12i;
    unsigned kprime, mb;
    sel12_block(ws + H12_OFF, epoch_ptr[0], &b12i, &kprime, &mb);
    if (b12i < 0) return;
    unsigned b12 = (unsigned)b12i;
    unsigned wlo, kpp;
    sel64_block(ws + H64_OFF, b12, (long long)kprime, &wlo, &kpp);
    unsigned thr;
    selwin_block(ws + HC_OFF, wlo, (long long)kpp, &thr);
    unsigned mband = mb + 2u;
    unsigned count = ws[CTRL_OFF + 3];

    long long tid = (long long)blockIdx.x * 256 + threadIdx.x;
    long long stride = (long long)gridDim.x * 256;

    if (count <= CAND_CAP) {
        // main path: fixup ONLY the candidates
        const unsigned* cand = ws + CAND_OFF;
        for (long long i = tid; i < (long long)count; i += stride) {
            unsigned idx = cand[i];
            unsigned u = ob[idx];
            unsigned udiff = (u > thr) ? u - thr : thr - u;
            if (udiff <= mband) {           // banded: exact decision
                unsigned eb = exact_bits(lg[idx]);
                if (eb > thr) ob[idx] = 0u;
            } else if (u > thr) {
                ob[idx] = 0u;               // rejected
            }
            // kept: tagged value stays (<=2 ulp off true loss, bf16 absorbs)
        }
    } else {
        // fallback: full-array rewrite
        long long n8 = n >> 3;
        u32x4* o4 = (u32x4*)ob;
        for (long long i = tid; i < n8; i += stride) {
            u32x4 ua = o4[2 * i];
            u32x4 ub = o4[2 * i + 1];
            unsigned us[8] = {ua.x, ua.y, ua.z, ua.w, ub.x, ub.y, ub.z, ub.w};
            unsigned vs[8];
            bool ch = false;
            long long base = i * 8;
#pragma unroll
            for (int c = 0; c < 8; ++c) {
                unsigned u = us[c];
                unsigned r = u;
                if (u & 1u) {               // unknown (incl. stored 1)
                    unsigned udiff = (u > thr) ? u - thr : thr - u;
                    if (udiff <= mband) {
                        unsigned eb = exact_bits(lg[base + c]);
                        r = (eb > thr) ? 0u : eb;
                    } else if (u > thr) {
                        r = 0u;
                    }
                }
                ch |= (r != u);
                vs[c] = r;
            }
            if (ch) {
                u32x4 va = {vs[0], vs[1], vs[2], vs[3]};
                u32x4 vb = {vs[4], vs[5], vs[6], vs[7]};
                o4[2 * i] = va;
                o4[2 * i + 1] = vb;
            }
        }
        if (tid == 0) {
            for (long long q = (n >> 3) << 3; q < n; ++q) {
                unsigned u = ob[q];
                if (u & 1u) {
                    unsigned udiff = (u > thr) ? u - thr : thr - u;
                    if (udiff <= mband) {
                        unsigned eb = exact_bits(lg[q]);
                        unsigned r = (eb > thr) ? 0u : eb;
                        if (r != u) ob[q] = r;
                    } else if (u > thr) {
                        ob[q] = 0u;
                    }
                }
            }
        }
    }
}

extern "C" void kernel_launch(void* const* d_in, const int* in_sizes, int n_in,
                              void* d_out, int out_size, void* d_ws, size_t ws_size,
                              hipStream_t stream) {
    const float* lg = (const float*)d_in[0];
    const float* tg = (const float*)d_in[1];
    const int* epoch = (const int*)d_in[2];
    float* out = (float*)d_out;
    unsigned* ob = (unsigned*)d_out;
    unsigned* ws = (unsigned*)d_ws;
    long long n = (long long)in_sizes[0];

    (void)hipMemsetAsync(d_ws, 0, (size_t)ZERO_WORDS * 4, stream);

    const int blocks = 2048, threads = 256;
    kA_store_hist<<<blocks, threads, 0, stream>>>(lg, tg, out, ws, n);
    kB_zero<<<blocks, threads, 0, stream>>>(lg, ob, ws, epoch, n);
    kC_histwin<<<1024, threads, 0, stream>>>(lg, ob, ws, epoch, n);
    kD_apply<<<blocks, threads, 0, stream>>>(lg, ob, ws, epoch, n);
}

// Round 18
// 217.437 us; speedup vs baseline: 1.2518x; 1.2518x over previous
//
#include <hip/hip_runtime.h>
#include <math.h>

typedef float    f32x4 __attribute__((ext_vector_type(4)));
typedef unsigned u32x4 __attribute__((ext_vector_type(4)));

// ws layout (uint32 words):
//   [0     .. 16384)  histC  (exact low-bits hist over selected 2^14 window)
//   [16384 .. 20480)  hist12 (top-12-bit histogram)
//   [20480 .. 20544)  hist64 (64 sub-bins of width 2^14 within selected b12)
//   [20544 .. 20560)  ctrl: [0]=b12 [1]=kprime [2]=thr_bits [3]=cand_count
//                           [4]=win_lo [5]=kpp [6]=m_bin
//   [20560 .. +CAP)   candidate INDICES (element idx) of selected b12
#define HC_OFF     0u
#define H12_OFF    16384u
#define H64_OFF    20480u
#define CTRL_OFF   20544u
#define ZERO_WORDS 20560u
#define CAND_OFF   20560u
#define CAND_CAP   900000u
#define LBUF       2048u

#define FLOOR_BITS 0x36000000u // bits(2^-19): below this, cheap unreliable

// TAGGING (r9/r14/r15/r16-proven): known -> loss_bits & ~1 (even, FINAL);
// unknown -> refined_bits | 1 (odd). <=1-ulp perturbation absorbed by
// margins (+2); 2^20/2^14 bin membership tag-invariant; exact threshold
// bits stay untagged.

// --- exact softplus (UNCHANGED from passing rounds 1-16) -----------------
__device__ __forceinline__ float softplus_exact(float x) {
    float ax = fabsf(x);
    float e = (float)exp(-(double)ax);
    float l = (float)log1p((double)e);
    return fmaxf(x, 0.0f) + l;
}
__device__ __forceinline__ unsigned exact_bits(float x) {
    return __float_as_uint(softplus_exact(x));
}

// --- refinement: cheap + margin-gated exact; DETERMINISTIC fn of x -------
__device__ __forceinline__ unsigned refine_core(float x, float ax, float e,
                                                float sp) {
    unsigned cb = __float_as_uint(sp);
    float mf = 64.0f + 8.0f * ax;
    if (x < 0.0f) mf += __builtin_amdgcn_rcpf(e);
    bool need = (cb < FLOOR_BITS) || (mf >= 524288.0f);
    if (!need) {
        unsigned m = (unsigned)mf;
        unsigned low = cb & 0xFFFFFu;
        need = (low < m) || (low >= 0x100000u - m);
    }
    if (need) cb = exact_bits(x);
    return cb;
}
__device__ __forceinline__ unsigned refine_A(float x) {
    float ax = fabsf(x);
    float e = __expf(-ax);
    float sp = fmaxf(x, 0.0f) + __logf(1.0f + e);
    return refine_core(x, ax, e, sp);
}

// --- kA per-element (r14/r15-proven) --------------------------------------
__device__ __forceinline__ unsigned kA_elem(float x, float t,
                                            unsigned* __restrict__ sh) {
    float ax = fabsf(x);
    float e = __expf(-ax);
    float sp = fmaxf(x, 0.0f) + __logf(1.0f + e);
    unsigned outb;
    if (isnan(t)) {
        unsigned cb = refine_core(x, ax, e, sp) | 1u;   // tag odd
        if (cb != 1u) atomicAdd(&sh[cb >> 20], 1u);     // count_nonzero
        outb = cb;
    } else {
        float loss = sp - x * t;                    // >= 0 always
        outb = __float_as_uint(loss) & ~1u;         // tag even: FINAL value
    }
    return outb;
}

// --- kA: stream logits+targets; store tagged bits to out; hist12 ---------
__global__ __launch_bounds__(256) void kA_store_hist(
    const float* __restrict__ lg, const float* __restrict__ tg,
    float* __restrict__ out, unsigned* __restrict__ ws, long long n) {
    __shared__ unsigned sh[4096];
    for (int i = threadIdx.x; i < 4096; i += 256) sh[i] = 0;
    __syncthreads();

    long long n8 = n >> 3;
    long long tid = (long long)blockIdx.x * 256 + threadIdx.x;
    long long stride = (long long)gridDim.x * 256;
    const f32x4* lg4 = (const f32x4*)lg;
    const f32x4* tg4 = (const f32x4*)tg;
    f32x4* out4 = (f32x4*)out;

    if (n8 % stride == 0) {
        long long iters = n8 / stride;
        f32x4 xa0, xb0, ta0, tb0, xa1, xb1, ta1, tb1;
        {
            long long i = tid;
            xa0 = lg4[2 * i]; xb0 = lg4[2 * i + 1];
            ta0 = __builtin_nontemporal_load(&tg4[2 * i]);
            tb0 = __builtin_nontemporal_load(&tg4[2 * i + 1]);
        }
        if (iters > 1) {
            long long i = tid + stride;
            xa1 = lg4[2 * i]; xb1 = lg4[2 * i + 1];
            ta1 = __builtin_nontemporal_load(&tg4[2 * i]);
            tb1 = __builtin_nontemporal_load(&tg4[2 * i + 1]);
        }
        for (long long it = 0; it < iters; ++it) {
            f32x4 pa, pb, pta, ptb;
            if (it + 2 < iters) {
                long long i = tid + (it + 2) * stride;
                pa = lg4[2 * i]; pb = lg4[2 * i + 1];
                pta = __builtin_nontemporal_load(&tg4[2 * i]);
                ptb = __builtin_nontemporal_load(&tg4[2 * i + 1]);
            }
            long long i = tid + it * stride;
            f32x4 oa, ob_;
            oa.x = __uint_as_float(kA_elem(xa0.x, ta0.x, sh));
            oa.y = __uint_as_float(kA_elem(xa0.y, ta0.y, sh));
            oa.z = __uint_as_float(kA_elem(xa0.z, ta0.z, sh));
            oa.w = __uint_as_float(kA_elem(xa0.w, ta0.w, sh));
            ob_.x = __uint_as_float(kA_elem(xb0.x, tb0.x, sh));
            ob_.y = __uint_as_float(kA_elem(xb0.y, tb0.y, sh));
            ob_.z = __uint_as_float(kA_elem(xb0.z, tb0.z, sh));
            ob_.w = __uint_as_float(kA_elem(xb0.w, tb0.w, sh));
            out4[2 * i] = oa;
            out4[2 * i + 1] = ob_;
            xa0 = xa1; xb0 = xb1; ta0 = ta1; tb0 = tb1;
            xa1 = pa; xb1 = pb; ta1 = pta; tb1 = ptb;
        }
    } else {
        for (long long i = tid; i < n8; i += stride) {
            f32x4 xa = lg4[2 * i], xb = lg4[2 * i + 1];
            f32x4 ta = tg4[2 * i], tb = tg4[2 * i + 1];
            f32x4 oa, ob_;
            oa.x = __uint_as_float(kA_elem(xa.x, ta.x, sh));
            oa.y = __uint_as_float(kA_elem(xa.y, ta.y, sh));
            oa.z = __uint_as_float(kA_elem(xa.z, ta.z, sh));
            oa.w = __uint_as_float(kA_elem(xa.w, ta.w, sh));
            ob_.x = __uint_as_float(kA_elem(xb.x, tb.x, sh));
            ob_.y = __uint_as_float(kA_elem(xb.y, tb.y, sh));
            ob_.z = __uint_as_float(kA_elem(xb.z, tb.z, sh));
            ob_.w = __uint_as_float(kA_elem(xb.w, tb.w, sh));
            out4[2 * i] = oa;
            out4[2 * i + 1] = ob_;
        }
    }
    if (tid == 0) {   // scalar tail
        for (long long q = (n >> 3) << 3; q < n; ++q)
            out[q] = __uint_as_float(kA_elem(lg[q], tg[q], sh));
    }
    __syncthreads();
    unsigned* hist12 = ws + H12_OFF;
    for (int q = threadIdx.x; q < 4096; q += 256)
        if (sh[q]) atomicAdd(&hist12[q], sh[q]);
}

// --- k2: select 12-bit bin; compute k, kprime, and bin-wide margin -------
__global__ __launch_bounds__(256) void k2_sel12(
    unsigned* __restrict__ ws, const int* __restrict__ epoch_ptr) {
    const unsigned* hist12 = ws + H12_OFF;
    unsigned* ctrl = ws + CTRL_OFF;
    __shared__ unsigned long long chunk[256];
    int t = threadIdx.x;
    unsigned long long s = 0;
    for (int j = 0; j < 16; ++j) s += hist12[t * 16 + j];
    chunk[t] = s;
    __syncthreads();
    if (t == 0) {
        unsigned long long tot = 0;
        for (int c = 0; c < 256; ++c) tot += chunk[c];
        int epoch = epoch_ptr[0];
        float percent = fminf((float)epoch * 0.1f, 1.0f);
        float nf = (float)tot;              // astype(float32)
        float kr = rintf(nf * percent);     // jnp.round half-to-even
        long long k = (long long)kr;        // astype(int32)
        if (k < 1) k = 1;

        long long cum = 0;
        int b = -1;
        long long kprime = 0;
        for (int c = 255; c >= 0; --c) {
            if (cum + (long long)chunk[c] >= k) {
                long long cc = cum;
                for (int j = 15; j >= 0; --j) {
                    unsigned v = hist12[c * 16 + j];
                    if (cc + (long long)v >= k) {
                        b = c * 16 + j;
                        kprime = k - cc;
                        break;
                    }
                    cc += v;
                }
                break;
            }
            cum += chunk[c];
        }
        ctrl[0] = (unsigned)b;
        ctrl[1] = (unsigned)kprime;
        if (b < 0) {
            ctrl[2] = 0u;                   // threshold = 0.0f
            ctrl[4] = 0xFFFFFFFFu;          // no window
            ctrl[6] = 0u;
        } else {
            unsigned lo12 = (unsigned)b << 20;
            double vlo = (double)__uint_as_float(lo12);
            double vhi = (double)__uint_as_float(lo12 + 0xFFFFFu);
            double mb = 1e9;
            if (vlo > 1e-30) {
                double xlo = vlo + log1p(-exp(-vlo)) - 0.001;  // inv_softplus
                double xhi = vhi + log1p(-exp(-vhi)) + 0.001;
                double axmax = fmax(fabs(xlo), fabs(xhi));
                mb = 64.0 + 8.0 * ceil(axmax);
                if (xlo < 0.0) mb += exp(fmin(-xlo, 30.0));
                mb *= 2.0;                  // safety factor
            }
            ctrl[6] = (mb >= 8192.0) ? 8192u : (unsigned)mb;
        }
    }
}

// --- kB: zero definite rejects (u >= hi12), hist64 + compact candidate idx
// 8-elem/iter depth-2 pipeline (kA's proven loop shape).
__device__ __forceinline__ void kB_elem(unsigned u, long long idx,
                                        unsigned lo12, unsigned hi12,
                                        unsigned medge,
                                        const float* __restrict__ lg,
                                        unsigned* __restrict__ ob,
                                        unsigned* __restrict__ sh,
                                        unsigned* __restrict__ buf,
                                        unsigned* __restrict__ lcnt) {
    if ((u & 1u) && u != 1u) {          // unknown, nonzero loss
        if (u >= hi12) {
            ob[idx] = 0u;               // definite reject: final zero
        } else if (u >= lo12) {         // candidate
            unsigned rB = u;
            unsigned d = u & 16383u;
            if (d < medge || d >= 16384u - medge)
                rB = exact_bits(lg[idx]) | 1u;   // edge: exact (tagged bin)
            atomicAdd(&sh[(rB >> 14) & 63u], 1u);
            unsigned li = atomicAdd(lcnt, 1u);
            if (li < LBUF) buf[li] = (unsigned)idx;
        }
    }
}

__global__ __launch_bounds__(256) void kB_zero(
    const float* __restrict__ lg, unsigned* __restrict__ ob,
    unsigned* __restrict__ ws, long long n) {
    unsigned b12 = ws[CTRL_OFF + 0];
    if (b12 == 0xFFFFFFFFu) return;
    unsigned lo12 = b12 << 20;
    unsigned hi12 = (b12 >= 4095u) ? 0xFFFFFFFFu : (lo12 + (1u << 20));
    unsigned medge = ws[CTRL_OFF + 6] + 2u;   // +2: tag absorption

    __shared__ unsigned sh[64];
    __shared__ unsigned buf[LBUF];
    __shared__ unsigned lcnt, gbase;
    if (threadIdx.x < 64) sh[threadIdx.x] = 0;
    if (threadIdx.x == 0) lcnt = 0;
    __syncthreads();

    unsigned* cand = ws + CAND_OFF;
    unsigned* cnt = ws + CTRL_OFF + 3;

    long long n8 = n >> 3;
    long long tid = (long long)blockIdx.x * 256 + threadIdx.x;
    long long stride = (long long)gridDim.x * 256;
    const u32x4* o4 = (const u32x4*)ob;

    if (n8 % stride == 0) {
        long long iters = n8 / stride;
        u32x4 ua0, ub0, ua1, ub1;
        {
            long long i = tid;
            ua0 = o4[2 * i]; ub0 = o4[2 * i + 1];
        }
        if (iters > 1) {
            long long i = tid + stride;
            ua1 = o4[2 * i]; ub1 = o4[2 * i + 1];
        }
        for (long long it = 0; it < iters; ++it) {
            u32x4 pa, pb;
            if (it + 2 < iters) {
                long long i = tid + (it + 2) * stride;
                pa = o4[2 * i]; pb = o4[2 * i + 1];
            }
            long long i = tid + it * stride;
            long long base = i * 8;
            kB_elem(ua0.x, base + 0, lo12, hi12, medge, lg, ob, sh, buf, &lcnt);
            kB_elem(ua0.y, base + 1, lo12, hi12, medge, lg, ob, sh, buf, &lcnt);
            kB_elem(ua0.z, base + 2, lo12, hi12, medge, lg, ob, sh, buf, &lcnt);
            kB_elem(ua0.w, base + 3, lo12, hi12, medge, lg, ob, sh, buf, &lcnt);
            kB_elem(ub0.x, base + 4, lo12, hi12, medge, lg, ob, sh, buf, &lcnt);
            kB_elem(ub0.y, base + 5, lo12, hi12, medge, lg, ob, sh, buf, &lcnt);
            kB_elem(ub0.z, base + 6, lo12, hi12, medge, lg, ob, sh, buf, &lcnt);
            kB_elem(ub0.w, base + 7, lo12, hi12, medge, lg, ob, sh, buf, &lcnt);
            ua0 = ua1; ub0 = ub1;
            ua1 = pa; ub1 = pb;
        }
    } else {
        for (long long i = tid; i < n8; i += stride) {
            u32x4 ua = o4[2 * i], ub = o4[2 * i + 1];
            long long base = i * 8;
            kB_elem(ua.x, base + 0, lo12, hi12, medge, lg, ob, sh, buf, &lcnt);
            kB_elem(ua.y, base + 1, lo12, hi12, medge, lg, ob, sh, buf, &lcnt);
            kB_elem(ua.z, base + 2, lo12, hi12, medge, lg, ob, sh, buf, &lcnt);
            kB_elem(ua.w, base + 3, lo12, hi12, medge, lg, ob, sh, buf, &lcnt);
            kB_elem(ub.x, base + 4, lo12, hi12, medge, lg, ob, sh, buf, &lcnt);
            kB_elem(ub.y, base + 5, lo12, hi12, medge, lg, ob, sh, buf, &lcnt);
            kB_elem(ub.z, base + 6, lo12, hi12, medge, lg, ob, sh, buf, &lcnt);
            kB_elem(ub.w, base + 7, lo12, hi12, medge, lg, ob, sh, buf, &lcnt);
        }
    }
    if (tid == 0) {   // scalar tail
        for (long long q = (n >> 3) << 3; q < n; ++q)
            kB_elem(ob[q], q, lo12, hi12, medge, lg, ob, sh, buf, &lcnt);
    }
    __syncthreads();
    if (threadIdx.x < 64 && sh[threadIdx.x])
        atomicAdd(&ws[H64_OFF + threadIdx.x], sh[threadIdx.x]);
    if (threadIdx.x == 0) {
        // on LDS overflow, poison count -> kC/kD take full-scan fallback
        unsigned add = (lcnt > LBUF) ? (CAND_CAP + 1u) : lcnt;
        gbase = atomicAdd(cnt, add);
    }
    __syncthreads();
    unsigned c2 = lcnt < LBUF ? lcnt : LBUF;
    for (unsigned q = threadIdx.x; q < c2; q += 256) {
        unsigned gi = gbase + q;
        if (gi < CAND_CAP) cand[gi] = buf[q];
    }
}

// --- k4: select 2^14-wide window ------------------------------------------
__global__ void k4_sel64(unsigned* __restrict__ ws) {
    unsigned* ctrl = ws + CTRL_OFF;
    if (ctrl[0] == 0xFFFFFFFFu) return;
    if (threadIdx.x == 0) {
        long long kprime = (long long)ctrl[1];
        long long cum = 0;
        int s = 0;
        long long kpp = 1;
        for (int j = 63; j >= 0; --j) {
            unsigned v = ws[H64_OFF + j];
            if (cum + (long long)v >= kprime) {
                s = j;
                kpp = kprime - cum;
                break;
            }
            cum += v;
        }
        ctrl[4] = (ctrl[0] << 20) + ((unsigned)s << 14);
        ctrl[5] = (unsigned)kpp;
    }
}

// --- kC: exact histogram over the selected window (idx-list scan) ---------
__global__ __launch_bounds__(256) void kC_histwin(
    const float* __restrict__ lg, const unsigned* __restrict__ ob,
    unsigned* __restrict__ ws, long long n) {
    unsigned wlo = ws[CTRL_OFF + 4];
    if (wlo == 0xFFFFFFFFu) return;
    unsigned whi = wlo + 16384u;
    unsigned medge = ws[CTRL_OFF + 6] + 2u;   // must match kB exactly
    unsigned b12 = ws[CTRL_OFF + 0];
    unsigned lo12 = b12 << 20;
    unsigned hi12 = (b12 >= 4095u) ? 0xFFFFFFFFu : (lo12 + (1u << 20));
    unsigned glo = (wlo - lo12 > medge) ? wlo - medge : lo12;
    unsigned ghi = (hi12 - whi > medge) ? whi + medge : hi12;
    unsigned count = ws[CTRL_OFF + 3];

    long long tid = (long long)blockIdx.x * 256 + threadIdx.x;
    long long stride = (long long)gridDim.x * 256;

    if (count <= CAND_CAP) {
        const unsigned* cand = ws + CAND_OFF;
        for (long long i = tid; i < (long long)count; i += stride) {
            unsigned idx = cand[i];
            float x = lg[idx];
            unsigned u = refine_A(x) | 1u;    // bit-identical to stored bits
            if (u >= glo && u < ghi) {
                unsigned eb = exact_bits(x);  // TRUE untagged bits
                unsigned rB = u;
                unsigned d = u & 16383u;
                if (d < medge || d >= 16384u - medge) rB = eb | 1u;
                if (rB >= wlo && rB < whi) {
                    unsigned off = eb - wlo;
                    if (off < 16384u) atomicAdd(&ws[HC_OFF + off], 1u);
                }
            }
        }
    } else {
        // overflow fallback: rescan full out array (never expected)
        long long n4 = n >> 2;
        const u32x4* o4 = (const u32x4*)ob;
        for (long long i = tid; i < n4; i += stride) {
            u32x4 u4 = o4[i];
            unsigned us[4] = {u4.x, u4.y, u4.z, u4.w};
#pragma unroll
            for (int c = 0; c < 4; ++c) {
                unsigned u = us[c];
                if ((u & 1u) && u != 1u && u >= glo && u < ghi) {
                    float x = lg[i * 4 + c];
                    unsigned eb = exact_bits(x);
                    unsigned rB = u;
                    unsigned d = u & 16383u;
                    if (d < medge || d >= 16384u - medge) rB = eb | 1u;
                    if (rB >= wlo && rB < whi) {
                        unsigned off = eb - wlo;
                        if (off < 16384u) atomicAdd(&ws[HC_OFF + off], 1u);
                    }
                }
            }
        }
        if (tid == 0) {
            for (long long q = (n4 << 2); q < n; ++q) {
                unsigned u = ob[q];
                if ((u & 1u) && u != 1u && u >= glo && u < ghi) {
                    unsigned eb = exact_bits(lg[q]);
                    unsigned rB = u;
                    unsigned d = u & 16383u;
                    if (d < medge || d >= 16384u - medge) rB = eb | 1u;
                    if (rB >= wlo && rB < whi) {
                        unsigned off = eb - wlo;
                        if (off < 16384u) atomicAdd(&ws[HC_OFF + off], 1u);
                    }
                }
            }
        }
    }
}

// --- k6: exact threshold bits from histC ----------------------------------
__global__ __launch_bounds__(1024) void k6_selwin(unsigned* __restrict__ ws) {
    unsigned* ctrl = ws + CTRL_OFF;
    if (ctrl[4] == 0xFFFFFFFFu) return;
    __shared__ unsigned long long csum[1024];
    int t = threadIdx.x;
    unsigned long long s = 0;
    for (int j = 0; j < 16; ++j) s += ws[HC_OFF + t * 16 + j];
    csum[t] = s;
    __syncthreads();
    if (t == 0) {
        long long kpp = (long long)ctrl[5];
        long long cum = 0;
        int sel = 0;
        long long rem = kpp;
        for (int c = 1023; c >= 0; --c) {
            if (cum + (long long)csum[c] >= kpp) {
                sel = c;
                rem = kpp - cum;
                break;
            }
            cum += csum[c];
        }
        long long cc = 0;
        int bsel = 0;
        for (int j = 15; j >= 0; --j) {
            unsigned v = ws[HC_OFF + sel * 16 + j];
            if (cc + (long long)v >= rem) {
                bsel = j;
                break;
            }
            cc += v;
        }
        ctrl[2] = ctrl[4] + (unsigned)(sel * 16 + bsel);
    }
}

// --- kD_cand: fixup ONLY the candidates (main path) ------------------------
__global__ __launch_bounds__(256) void kD_cand(
    const float* __restrict__ lg, unsigned* __restrict__ ob,
    const unsigned* __restrict__ ws) {
    unsigned count = ws[CTRL_OFF + 3];
    if (count > CAND_CAP) return;           // fallback kernel handles it
    unsigned thr = ws[CTRL_OFF + 2];
    unsigned mband = ws[CTRL_OFF + 6] + 2u;
    const unsigned* cand = ws + CAND_OFF;

    long long tid = (long long)blockIdx.x * 256 + threadIdx.x;
    long long stride = (long long)gridDim.x * 256;
    for (long long i = tid; i < (long long)count; i += stride) {
        unsigned idx = cand[i];
        unsigned u = ob[idx];
        unsigned udiff = (u > thr) ? u - thr : thr - u;
        if (udiff <= mband) {               // banded: exact decision
            unsigned eb = exact_bits(lg[idx]);
            if (eb > thr) ob[idx] = 0u;
        } else if (u > thr) {
            ob[idx] = 0u;                   // rejected
        }
        // kept: tagged value stays (<=2 ulp off true loss, bf16 absorbs)
    }
}

// --- kD_full: fallback full-array rewrite (cand overflow only) -------------
__device__ __forceinline__ unsigned kD_elem(unsigned u, unsigned thr,
                                            unsigned mband,
                                            const float* __restrict__ lg,
                                            long long idx, bool* changed) {
    if (!(u & 1u)) return u;                        // known/zero: final
    unsigned udiff = (u > thr) ? u - thr : thr - u;
    if (udiff <= mband) {
        unsigned eb = exact_bits(lg[idx]);
        unsigned r = (eb > thr) ? 0u : eb;
        *changed |= (r != u);
        return r;
    }
    if (u > thr) { *changed = true; return 0u; }
    return u;
}

__global__ __launch_bounds__(256) void kD_full(
    const float* __restrict__ lg, unsigned* __restrict__ ob,
    const unsigned* __restrict__ ws, long long n) {
    if (ws[CTRL_OFF + 3] <= CAND_CAP) return;       // main path handled it
    unsigned thr = ws[CTRL_OFF + 2];
    unsigned mband = ws[CTRL_OFF + 6] + 2u;

    long long n8 = n >> 3;
    long long tid = (long long)blockIdx.x * 256 + threadIdx.x;
    long long stride = (long long)gridDim.x * 256;
    u32x4* o4 = (u32x4*)ob;

    for (long long i = tid; i < n8; i += stride) {
        u32x4 ua = o4[2 * i];
        u32x4 ub = o4[2 * i + 1];
        u32x4 va, vb;
        bool chA = false, chB = false;
        long long base = i * 8;
        va.x = kD_elem(ua.x, thr, mband, lg, base + 0, &chA);
        va.y = kD_elem(ua.y, thr, mband, lg, base + 1, &chA);
        va.z = kD_elem(ua.z, thr, mband, lg, base + 2, &chA);
        va.w = kD_elem(ua.w, thr, mband, lg, base + 3, &chA);
        vb.x = kD_elem(ub.x, thr, mband, lg, base + 4, &chB);
        vb.y = kD_elem(ub.y, thr, mband, lg, base + 5, &chB);
        vb.z = kD_elem(ub.z, thr, mband, lg, base + 6, &chB);
        vb.w = kD_elem(ub.w, thr, mband, lg, base + 7, &chB);
        if (chA) o4[2 * i] = va;
        if (chB) o4[2 * i + 1] = vb;
    }
    if (tid == 0) {
        for (long long q = (n >> 3) << 3; q < n; ++q) {
            bool ch = false;
            unsigned r = kD_elem(ob[q], thr, mband, lg, q, &ch);
            if (ch) ob[q] = r;
        }
    }
}

extern "C" void kernel_launch(void* const* d_in, const int* in_sizes, int n_in,
                              void* d_out, int out_size, void* d_ws, size_t ws_size,
                              hipStream_t stream) {
    const float* lg = (const float*)d_in[0];
    const float* tg = (const float*)d_in[1];
    const int* epoch = (const int*)d_in[2];
    float* out = (float*)d_out;
    unsigned* ob = (unsigned*)d_out;
    unsigned* ws = (unsigned*)d_ws;
    long long n = (long long)in_sizes[0];

    (void)hipMemsetAsync(d_ws, 0, (size_t)ZERO_WORDS * 4, stream);

    const int blocks = 2048, threads = 256;
    kA_store_hist<<<blocks, threads, 0, stream>>>(lg, tg, out, ws, n);
    k2_sel12<<<1, 256, 0, stream>>>(ws, epoch);
    kB_zero<<<blocks, threads, 0, stream>>>(lg, ob, ws, n);
    k4_sel64<<<1, 64, 0, stream>>>(ws);
    kC_histwin<<<1024, threads, 0, stream>>>(lg, ob, ws, n);
    k6_selwin<<<1, 1024, 0, stream>>>(ws);
    kD_cand<<<256, threads, 0, stream>>>(lg, ob, ws);
    kD_full<<<blocks, threads, 0, stream>>>(lg, ob, ws, n);
}